// Round 22
// baseline (114.525 us; speedup 1.0000x reference)
//
#include <hip/hip_runtime.h>

#define IN_DIM  128
#define HIDDEN  512
#define NCLASS  10
#define TSTEPS  512
#define BATCH   512
#define BETA    0.9f
#define THRESH  0.15f

typedef __attribute__((ext_vector_type(8))) short bf16x8;
typedef __attribute__((ext_vector_type(4))) float f32x4;

__device__ __forceinline__ unsigned short f2bf_rne(float f) {
    unsigned int u = __float_as_uint(f);
    u += 0x7FFFu + ((u >> 16) & 1u);
    return (unsigned short)(u >> 16);
}
__device__ __forceinline__ float bf2f(unsigned short h) {
    return __uint_as_float(((unsigned int)h) << 16);
}

// 8 f32 (scaled by s) -> single bf16x8 (RNE)
__device__ __forceinline__ bf16x8 cvt8(const float4 a, const float4 b, float s) {
    float v[8] = {a.x * s, a.y * s, a.z * s, a.w * s,
                  b.x * s, b.y * s, b.z * s, b.w * s};
    bf16x8 o;
#pragma unroll
    for (int e = 0; e < 8; ++e) o[e] = (short)f2bf_rne(v[e]);
    return o;
}

// 8 f32 -> hi bf16x8 + residual-lo bf16x8 (for W1, register-resident)
__device__ __forceinline__ void cvt8s(const float4 a, const float4 b,
                                      bf16x8* hi, bf16x8* lo) {
    float v[8] = {a.x, a.y, a.z, a.w, b.x, b.y, b.z, b.w};
#pragma unroll
    for (int e = 0; e < 8; ++e) {
        unsigned short h = f2bf_rne(v[e]);
        (*hi)[e] = (short)h;
        (*lo)[e] = (short)f2bf_rne(v[e] - bf2f(h));
    }
}

// ---------- Pass 1: repack x into LANE-LINEAR bf16 fragment tiles ----------
// tile(bblk,t) = 4KB: 2048 shorts. Element for wave-lane i, k-chunk kf at
// short index kf*512 + i*8 => per-wave 1KB contiguous loads.
__global__ __launch_bounds__(256, 4) void conv_x3(
    const float* __restrict__ x, unsigned short* __restrict__ xt)
{
    const int bid  = blockIdx.x;          // bblk*512 + t
    const int bblk = bid >> 9;
    const int t    = bid & 511;
    const int g    = threadIdx.x;         // 0..255
    const int kf   = g >> 6;
    const int i    = g & 63;
    const int l15  = i & 15;
    const int lg   = i >> 4;

    const float* src = x + ((size_t)(bblk * 16 + l15) * TSTEPS + t) * IN_DIM
                         + kf * 32 + lg * 8;
    const float4* p = reinterpret_cast<const float4*>(src);
    unsigned short* tile = xt + ((size_t)bblk * TSTEPS + t) * 2048;
    *(bf16x8*)(tile + g * 8) = cvt8(p[0], p[1], 2.0f);
}

// ---------- Pass 2: fused SNN, direct global->reg, reordered pipeline ----
// R21 (no LDS, no barriers, free-running waves) + R22 micro-schedule:
// wait(16) -> setprio(1) MFMA setprio(0) -> STG next pair -> REC.
// STG+REC fill the MFMA tail latency; setprio favors the MFMA-entering
// wave among free-running peers (T5 regime: role diversity exists here,
// unlike the barrier-locked variants where it was null).
__global__ __launch_bounds__(256, 1) void snn_mfma_a(
    const unsigned short* __restrict__ xt,
    const float* __restrict__ W1, const float* __restrict__ b1,
    float* __restrict__ cnt_ws)
{
    const int bid  = blockIdx.x;
    const int hblk = bid >> 5;     // 0..7 ; bid%8==bblk%8 -> x-sharers co-XCD
    const int bblk = bid & 31;
    const int b0   = bblk * 16;
    const int tid  = threadIdx.x;  // 0..255
    const int wave = tid >> 6;     // 0..3
    const int lane = tid & 63;
    const int l15  = lane & 15;
    const int lg   = lane >> 4;
    const int hbase = hblk * 64 + wave * 16;

    // ---- W fragments hi+lo (register-resident precision split) ----
    bf16x8 whi[4], wlo[4];
    {
        const float* wp = W1 + (size_t)(hbase + l15) * IN_DIM + lg * 8;
#pragma unroll
        for (int kf = 0; kf < 4; ++kf) {
            const float4* p = reinterpret_cast<const float4*>(wp + kf * 32);
            cvt8s(p[0], p[1], &whi[kf], &wlo[kf]);
        }
    }
    const float b1h = b1[hbase + l15];
    const f32x4 B1 = {b1h, b1h, b1h, b1h};   // persistent C-in seeds
    const f32x4 Z0 = {0.f, 0.f, 0.f, 0.f};

    // wave-uniform SGPR base; per-lane 32-bit running voffset (issue order)
    const unsigned short* gbase = xt + (size_t)bblk * TSTEPS * 2048;
    unsigned voff = (unsigned)(lane * 16);

    f32x4 mem = {0.f, 0.f, 0.f, 0.f}, cnt = {0.f, 0.f, 0.f, 0.f};

// one fragment load: dst <- gbase + voff + imm   (asm: order-pinned)
#define GLD(IMM, DST)                                                          \
    asm volatile("global_load_dwordx4 %0, %1, %2 offset:%c3"                   \
                 : "=&v"(DST) : "v"(voff), "s"(gbase), "i"(IMM))

// issue one tile (4 frag loads) into slot set F; advance voff to next tile
#define STG(F)                                                                 \
    GLD(0, F[0]); GLD(1024, F[1]); GLD(2048, F[2]); GLD(3072, F[3]);           \
    voff += 4096;

// 16 MFMAs for timesteps t (F0) and t+1 (F1), 4 independent chains.
#define MFMA_PAIR(F0, F1, H0, L0, H1, L1)                                      \
    H0 = __builtin_amdgcn_mfma_f32_16x16x32_bf16(F0[0], whi[0], B1, 0, 0, 0);  \
    H1 = __builtin_amdgcn_mfma_f32_16x16x32_bf16(F1[0], whi[0], B1, 0, 0, 0);  \
    L0 = __builtin_amdgcn_mfma_f32_16x16x32_bf16(F0[0], wlo[0], Z0, 0, 0, 0);  \
    L1 = __builtin_amdgcn_mfma_f32_16x16x32_bf16(F1[0], wlo[0], Z0, 0, 0, 0);  \
    _Pragma("unroll")                                                          \
    for (int kf = 1; kf < 4; ++kf) {                                           \
        H0 = __builtin_amdgcn_mfma_f32_16x16x32_bf16(F0[kf], whi[kf], H0, 0, 0, 0); \
        H1 = __builtin_amdgcn_mfma_f32_16x16x32_bf16(F1[kf], whi[kf], H1, 0, 0, 0); \
        L0 = __builtin_amdgcn_mfma_f32_16x16x32_bf16(F0[kf], wlo[kf], L0, 0, 0, 0); \
        L1 = __builtin_amdgcn_mfma_f32_16x16x32_bf16(F1[kf], wlo[kf], L1, 0, 0, 0); \
    }

// LIF recurrence (snntorch order), sequential across t by nature.
#define REC(PH, PL)                                                            \
    _Pragma("unroll")                                                          \
    for (int r = 0; r < 4; ++r) {                                              \
        float cur = PH[r] + PL[r];                                             \
        float dec = fmaf(BETA, mem[r], cur);                                   \
        mem[r] = (mem[r] > THRESH) ? (dec - THRESH) : dec;                     \
        cnt[r] += (mem[r] > THRESH) ? 1.0f : 0.0f;                             \
    }

// Pair step: wait(16) = oldest 2 tiles (t,t+1) landed, 4 tiles (t+2..t+5)
// in flight. MFMA first (setprio-wrapped), THEN stage t+6,t+7 and REC --
// both fill the MFMA tail latency before next pair's consumption.
#define PAIR(C0, C1, N0, N1)                                                   \
    {                                                                          \
        asm volatile("s_waitcnt vmcnt(16)" ::: "memory");                      \
        __builtin_amdgcn_sched_barrier(0);                                     \
        __builtin_amdgcn_s_setprio(1);                                         \
        MFMA_PAIR(C0, C1, hA, lA, hB, lB)                                      \
        __builtin_amdgcn_s_setprio(0);                                         \
        STG(N0)                                                                \
        STG(N1)                                                                \
        REC(hA, lA)                                                            \
        REC(hB, lB)                                                            \
    }

    // 8 fragment slot-sets (tiles mod 8) + 4 acc chains
    bf16x8 s0[4], s1[4], s2[4], s3[4], s4[4], s5[4], s6[4], s7[4];
    f32x4 hA, lA, hB, lB;

    // prologue: drain W/b1 loads (their vmcnt must not mix with pipeline),
    // then issue tiles 0..5 (24 loads outstanding).
    asm volatile("s_waitcnt vmcnt(0)" ::: "memory");
    STG(s0) STG(s1) STG(s2) STG(s3) STG(s4) STG(s5)

    // 4 pairs (8 t) per window; slots rotate mod 8 -> all compile-time.
    for (int w = 0; w < TSTEPS / 8; ++w) {
        PAIR(s0, s1, s6, s7)
        PAIR(s2, s3, s0, s1)
        PAIR(s4, s5, s2, s3)
        PAIR(s6, s7, s4, s5)
    }
#undef PAIR
#undef REC
#undef MFMA_PAIR
#undef STG
#undef GLD

    // store spike counts; C-layout row = lg*4+r, col = l15
    float* cp = cnt_ws + (size_t)b0 * HIDDEN + hbase + l15;
#pragma unroll
    for (int r = 0; r < 4; ++r)
        cp[(size_t)(lg * 4 + r) * HIDDEN] = cnt[r];
}

// ---------- Fallback (proven R2 path) if ws too small ----------
__global__ __launch_bounds__(256, 1) void snn_mfma_lds(
    const float* __restrict__ x, const float* __restrict__ W1,
    const float* __restrict__ b1, float* __restrict__ cnt_ws)
{
    __shared__ short ldsA[2][2][16 * IN_DIM];
    const int bid  = blockIdx.x;
    const int hblk = bid >> 5;
    const int bblk = bid & 31;
    const int b0   = bblk * 16;
    const int tid  = threadIdx.x;
    const int wave = tid >> 6;
    const int lane = tid & 63;
    const int l15  = lane & 15;
    const int lg   = lane >> 4;
    const int hbase = hblk * 64 + wave * 16;

    bf16x8 whi[4], wlo[4];
    {
        const float* wp = W1 + (size_t)(hbase + l15) * IN_DIM + lg * 8;
#pragma unroll
        for (int kf = 0; kf < 4; ++kf) {
            const float4* p = reinterpret_cast<const float4*>(wp + kf * 32);
            cvt8s(p[0], p[1], &whi[kf], &wlo[kf]);
        }
    }
    const float b1h = b1[hbase + l15];
    const int m_w  = wave * 4 + lg;
    const int widx = m_w * IN_DIM + ((l15 ^ (m_w & 7)) * 8);
    const float* xrow = x + ((size_t)(b0 + m_w) * TSTEPS) * IN_DIM + l15 * 8;
    int ridx[4];
#pragma unroll
    for (int kf = 0; kf < 4; ++kf)
        ridx[kf] = l15 * IN_DIM + (((lg + 4 * kf) ^ (l15 & 7)) * 8);

    f32x4 mem = {0.f, 0.f, 0.f, 0.f};
    f32x4 cnt = {0.f, 0.f, 0.f, 0.f};
    {
        const float4* p = reinterpret_cast<const float4*>(xrow);
        *(bf16x8*)&ldsA[0][0][widx] = cvt8(p[0], p[1], 2.0f);
    }
    float4 rA0, rA1, rB0, rB1;
    {
        const float4* p1 = reinterpret_cast<const float4*>(xrow + 1 * IN_DIM);
        rA0 = p1[0]; rA1 = p1[1];
        const float4* p2 = reinterpret_cast<const float4*>(xrow + 2 * IN_DIM);
        rB0 = p2[0]; rB1 = p2[1];
    }
    __syncthreads();

#define SNN_BODY(T_CUR, RC0, RC1)                                              \
    {                                                                          \
        const int buf = (T_CUR) & 1;                                           \
        if ((T_CUR) + 1 < TSTEPS) {                                            \
            *(bf16x8*)&ldsA[buf ^ 1][0][widx] = cvt8(RC0, RC1, 2.0f);          \
        }                                                                      \
        bf16x8 ahi[4];                                                         \
        _Pragma("unroll")                                                      \
        for (int kf = 0; kf < 4; ++kf)                                         \
            ahi[kf] = *(const bf16x8*)&ldsA[buf][0][ridx[kf]];                 \
        {                                                                      \
            int tld = (T_CUR) + 3;                                             \
            if (tld > TSTEPS - 1) tld = TSTEPS - 1;                            \
            const float4* p = reinterpret_cast<const float4*>(                 \
                xrow + (size_t)tld * IN_DIM);                                  \
            RC0 = p[0]; RC1 = p[1];                                            \
        }                                                                      \
        f32x4 chh = {b1h, b1h, b1h, b1h};                                      \
        f32x4 chl = {0.f, 0.f, 0.f, 0.f};                                      \
        _Pragma("unroll")                                                      \
        for (int kf = 0; kf < 4; ++kf) {                                       \
            chh = __builtin_amdgcn_mfma_f32_16x16x32_bf16(ahi[kf], whi[kf], chh, 0, 0, 0); \
            chl = __builtin_amdgcn_mfma_f32_16x16x32_bf16(ahi[kf], wlo[kf], chl, 0, 0, 0); \
        }                                                                      \
        _Pragma("unroll")                                                      \
        for (int r = 0; r < 4; ++r) {                                          \
            float cur = chh[r] + chl[r];                                       \
            float dec = fmaf(BETA, mem[r], cur);                               \
            mem[r] = (mem[r] > THRESH) ? (dec - THRESH) : dec;                 \
            cnt[r] += (mem[r] > THRESH) ? 1.0f : 0.0f;                         \
        }                                                                      \
        __syncthreads();                                                       \
    }

    for (int t = 0; t < TSTEPS; t += 2) {
        SNN_BODY(t,     rA0, rA1)
        SNN_BODY(t + 1, rB0, rB1)
    }
#undef SNN_BODY

    float* cp = cnt_ws + (size_t)b0 * HIDDEN + hbase + l15;
#pragma unroll
    for (int r = 0; r < 4; ++r)
        cp[(size_t)(lg * 4 + r) * HIDDEN] = cnt[r];
}

// out[b,c] = (sum_h cnt[b,h] * W2[c,h]) / T + b2[c]
__global__ __launch_bounds__(64, 1) void snn_out(
    const float* __restrict__ cnt_ws, const float* __restrict__ W2,
    const float* __restrict__ b2, float* __restrict__ out)
{
    const int b = blockIdx.x;
    const int lane = threadIdx.x;
    float c8[8];
#pragma unroll
    for (int j = 0; j < 8; ++j)
        c8[j] = cnt_ws[(size_t)b * HIDDEN + lane + 64 * j];
#pragma unroll
    for (int c = 0; c < NCLASS; ++c) {
        float s = 0.f;
#pragma unroll
        for (int j = 0; j < 8; ++j)
            s = fmaf(c8[j], W2[c * HIDDEN + lane + 64 * j], s);
#pragma unroll
        for (int off = 32; off >= 1; off >>= 1)
            s += __shfl_xor(s, off, 64);
        if (lane == c)
            out[(size_t)b * NCLASS + c] = s * (1.0f / (float)TSTEPS) + b2[c];
    }
}

extern "C" void kernel_launch(void* const* d_in, const int* in_sizes, int n_in,
                              void* d_out, int out_size, void* d_ws, size_t ws_size,
                              hipStream_t stream) {
    const float* x  = (const float*)d_in[0];
    const float* W1 = (const float*)d_in[1];
    const float* b1 = (const float*)d_in[2];
    const float* W2 = (const float*)d_in[3];
    const float* b2 = (const float*)d_in[4];
    float* out = (float*)d_out;

    const size_t NX = (size_t)BATCH * TSTEPS * IN_DIM;      // 33.55M elems
    float* cnt_ws = (float*)d_ws;                           // [B, H], 1 MB
    unsigned short* xt = (unsigned short*)((char*)d_ws + (1u << 20));
    // +8 pad tiles (16K shorts): prefetch past t=511 is valid-but-unused
    const size_t need = (1u << 20) + (NX + 8 * 2048) * sizeof(unsigned short);

    if (ws_size >= need) {
        conv_x3<<<dim3(32 * TSTEPS), dim3(256), 0, stream>>>(x, xt);
        snn_mfma_a<<<dim3(256), dim3(256), 0, stream>>>(xt, W1, b1, cnt_ws);
    } else {
        snn_mfma_lds<<<dim3(256), dim3(256), 0, stream>>>(x, W1, b1, cnt_ws);
    }
    snn_out<<<dim3(BATCH), dim3(64), 0, stream>>>(cnt_ws, W2, b2, out);
}